// Round 7
// baseline (206.976 us; speedup 1.0000x reference)
//
#include <hip/hip_runtime.h>
#include <math.h>

#define N_LAYERS 8
#define LOG2E2 2.8853900817779268f   // 2*log2(e)
#define NLOG2E 1.4426950408889634f   // log2(e)
#define UCLAMP 24.0f                  // exp2 clamp: keeps e0*e1 < 2^49 finite for Montgomery
#define BLK 256

#if __has_builtin(__builtin_amdgcn_exp2f)
__device__ __forceinline__ float exp2_fast(float x) { return __builtin_amdgcn_exp2f(x); }
#else
__device__ __forceinline__ float exp2_fast(float x) { return __expf(0.6931471805599453f * x); }
#endif

// d_ws float layout (93 floats):
//  layer l in 0..8 at fp[10*l ..]:  {W~00,W~01,W~10,W~11, b~0,b~1, m2s0,m2s1, spt0,spt1}
//    where W~ = 2log2e*W, b~ = 2log2e*b, m2s = -2*scale, spt = scale+shift
//    l=0 is the input layer (W0,b0,scale0,shift0), l=1..8 the hidden layers.
//  fp[90..92] = {Wf0, Wf1, bf}
//
// tanh(u) = 1 - 2/(1+exp2(2log2e*u)); z' = tanh*s + t = fmaf(-2s, i, s+t)
// with i = 1/(1+exp2(u~)). This exact formula is the one the previous
// (table-based) kernels used for the input layer — numerically validated.
__global__ __launch_bounds__(64) void setup_meta(
    const float* __restrict__ W0, const float* __restrict__ b0,
    const float* __restrict__ s0, const float* __restrict__ t0,
    const float* __restrict__ Ws, const float* __restrict__ bs,
    const float* __restrict__ ss, const float* __restrict__ ts,
    const float* __restrict__ Wf, const float* __restrict__ bf,
    float* __restrict__ fp) {
    if (threadIdx.x == 0 && blockIdx.x == 0) {
        // input layer -> slot 0
        fp[0] = LOG2E2 * W0[0]; fp[1] = LOG2E2 * W0[1];
        fp[2] = LOG2E2 * W0[2]; fp[3] = LOG2E2 * W0[3];
        fp[4] = LOG2E2 * b0[0]; fp[5] = LOG2E2 * b0[1];
        fp[6] = -2.0f * s0[0];  fp[7] = -2.0f * s0[1];
        fp[8] = s0[0] + t0[0];  fp[9] = s0[1] + t0[1];
        // hidden layers -> slots 1..8  (Ws already clipped at construction)
        for (int l = 0; l < N_LAYERS; ++l) {
            float* q = fp + 10 * (l + 1);
            q[0] = LOG2E2 * Ws[4 * l + 0]; q[1] = LOG2E2 * Ws[4 * l + 1];
            q[2] = LOG2E2 * Ws[4 * l + 2]; q[3] = LOG2E2 * Ws[4 * l + 3];
            q[4] = LOG2E2 * bs[2 * l + 0]; q[5] = LOG2E2 * bs[2 * l + 1];
            q[6] = -2.0f * ss[2 * l + 0];  q[7] = -2.0f * ss[2 * l + 1];
            q[8] = ss[2 * l + 0] + ts[2 * l + 0];
            q[9] = ss[2 * l + 1] + ts[2 * l + 1];
        }
        fp[90] = Wf[0]; fp[91] = Wf[1]; fp[92] = bf[0];
    }
}

// Direct 9-layer evaluation, all in registers. Per layer: 4 fma + 2 min +
// 2 exp2 + 2 add + Montgomery-2 (1 rcp + 3 mul) + 2 fma. fp reads are
// wave-uniform -> scalar loads/SGPRs. u~ clamp at 24: tanh error <= 1.2e-7;
// negative underflow (exp2 -> 0, d=1) is exact.
__device__ __forceinline__ float net_eval(const float* __restrict__ fp,
                                          float z0, float z1) {
#pragma unroll
    for (int l = 0; l < N_LAYERS + 1; ++l) {
        const float* q = fp + 10 * l;
        float u0 = fmaf(z0, q[0], fmaf(z1, q[1], q[4]));
        float u1 = fmaf(z0, q[2], fmaf(z1, q[3], q[5]));
        float d0 = exp2_fast(fminf(u0, UCLAMP)) + 1.0f;
        float d1 = exp2_fast(fminf(u1, UCLAMP)) + 1.0f;
        float R  = __builtin_amdgcn_rcpf(d0 * d1);
        float i0 = R * d1;
        float i1 = R * d0;
        z0 = fmaf(q[6], i0, q[8]);
        z1 = fmaf(q[7], i1, q[9]);
    }
    return fmaf(z0, fp[90], fmaf(z1, fp[91], fp[92]));
}

// No LDS, no table, no gather: pure VALU/trans pipes. 4 independent
// point-chains per k-iteration give in-wave ILP; TLP covers the rest.
// Plain __launch_bounds__ (no min-waves arg -- r1/r4/r5: that flag forces
// min-pressure scheduling; here compiler is free, expected ~48-80 VGPR).
__global__ __launch_bounds__(BLK) void fraud_kernel(
    const float4* __restrict__ x4, const float4* __restrict__ y4,
    const float* __restrict__ fp, float2* __restrict__ out2, int stride)
{
    int tid = blockIdx.x * BLK + threadIdx.x;
#pragma unroll
    for (int k = 0; k < 4; ++k) {
        int g = tid + k * stride;        // coalesced float4 per lane
        float4 xa = x4[g], ya = y4[g];   // 2 pairs

        float fxA = net_eval(fp, xa.x, xa.y);
        float fyA = net_eval(fp, ya.x, ya.y);
        float dxA = xa.x - ya.x, dyA = xa.y - ya.y;
        float rA = exp2_fast(-NLOG2E * fmaf(dxA, dxA, dyA * dyA));
        float resA = rA * fxA * fyA;

        float fxB = net_eval(fp, xa.z, xa.w);
        float fyB = net_eval(fp, ya.z, ya.w);
        float dxB = xa.z - ya.z, dyB = xa.w - ya.w;
        float rB = exp2_fast(-NLOG2E * fmaf(dxB, dxB, dyB * dyB));
        float resB = rB * fxB * fyB;

        out2[g] = make_float2(resA, resB);
    }
}

extern "C" void kernel_launch(void* const* d_in, const int* in_sizes, int n_in,
                              void* d_out, int out_size, void* d_ws, size_t ws_size,
                              hipStream_t stream) {
    const float* x  = (const float*)d_in[0];
    const float* y  = (const float*)d_in[1];
    const float* W0 = (const float*)d_in[2];
    const float* b0 = (const float*)d_in[3];
    const float* s0 = (const float*)d_in[4];
    const float* t0 = (const float*)d_in[5];
    const float* Ws = (const float*)d_in[6];
    const float* bs = (const float*)d_in[7];
    const float* ss = (const float*)d_in[8];
    const float* ts = (const float*)d_in[9];
    const float* Wf = (const float*)d_in[10];
    const float* bf = (const float*)d_in[11];
    float* out = (float*)d_out;
    float* fp  = (float*)d_ws;

    hipLaunchKernelGGL(setup_meta, dim3(1), dim3(64), 0, stream,
                       W0, b0, s0, t0, Ws, bs, ss, ts, Wf, bf, fp);

    int n       = out_size;          // 8,388,608 pairs
    int ngroups = n / 2;             // float4-groups of 2 pairs
    int threads = ngroups / 4;       // 4 groups per thread = 8 pairs (2^20)
    dim3 block(BLK);
    dim3 grid(threads / BLK);        // 2^20 / 256 = 4096, exact
    hipLaunchKernelGGL(fraud_kernel, grid, block, 0, stream,
                       (const float4*)x, (const float4*)y, fp,
                       (float2*)out, threads);
}